// Round 3
// baseline (331.070 us; speedup 1.0000x reference)
//
#include <hip/hip_runtime.h>

// ---------------------------------------------------------------------------
// out[n] = x_n^T A x_n / (x_n^T x_n),  A = Re(U^H Z U), U = full circuit unitary
//
// R8 -> R9: R8's cooperative launch never executed (absmax == max|ref| ==
// all-zero output => launch rejected; return code unchecked). R9 keeps the
// fused single-kernel structure but drops the cooperative API:
//   - manual device-scope barrier, legal because the grid is HW-co-resident
//     by construction: 64 KB LDS/block -> exactly 2 blocks/CU x 256 CU = 512
//     = GRID. Counters in ws, zeroed by an in-graph hipMemsetAsync before
//     the kernel (same stream, capture-safe).
//   - sim rewritten register/shuffle-resident (1 wave/column, no LDS, no
//     __syncthreads): lane l holds amps l and l+64; qubit0 gates in-lane,
//     others via __shfl_xor; CNOT = cndmask/shfl swap. ~1 us, overlapped
//     under the X-tile prefetch DMAs.
//   - phase C byte-identical to R7's verified counted-vmcnt loop; vmcnt
//     base pinned to 0 after barrier 2.
// Predicted: passes (absmax ~2^-9), dur_us 208 -> ~190. If delta < 5 us the
// rest is harness-fixed overhead (512 MB poison fills = 77 us each).
// ---------------------------------------------------------------------------

#define N_QUBITS 7
#define DIM 128
#define N_LAYERS 4
#define BATCH 262144
#define GRID 512
#define ROWS 32                          // rows per X tile
#define ITERS (BATCH / (GRID * ROWS))    // 16
#define DEPTH 4                          // X tile buffers in LDS

typedef short short8 __attribute__((ext_vector_type(8)));
typedef float f32x4 __attribute__((ext_vector_type(4)));
typedef unsigned int u32;
typedef __attribute__((address_space(1))) const u32 g_u32;
typedef __attribute__((address_space(3))) u32 l_u32;

__device__ __forceinline__ unsigned short f2bf(float f) {
  unsigned u = __builtin_bit_cast(unsigned, f);
  u += 0x7fffu + ((u >> 16) & 1u);   // RNE
  return (unsigned short)(u >> 16);
}

// [bf16(x) | bf16(y)<<16]: round-half-up add + v_perm byte select
__device__ __forceinline__ unsigned pk2(float x, float y) {
  unsigned ux = __builtin_bit_cast(unsigned, x) + 0x8000u;
  unsigned uy = __builtin_bit_cast(unsigned, y) + 0x8000u;
  return __builtin_amdgcn_perm(uy, ux, 0x07060302u);
}

__device__ __forceinline__ short8 pack_bf16(float4 lo, float4 hi) {
  uint4 d;
  d.x = pk2(lo.x, lo.y);
  d.y = pk2(lo.z, lo.w);
  d.z = pk2(hi.x, hi.y);
  d.w = pk2(hi.z, hi.w);
  return __builtin_bit_cast(short8, d);
}

// ---------------------------------------------------------------------------
// Manual grid barrier. Safe ONLY because all GRID blocks are HW-co-resident
// (LDS 64 KB/block -> 2 blocks/CU -> capacity 512 = GRID). Every thread
// fences (device scope) so all block stores are L2-visible before the
// leader's release add; acquire load + fence on exit.
// ---------------------------------------------------------------------------
__device__ __forceinline__ void grid_bar(unsigned* bar, unsigned target) {
  __threadfence();
  __syncthreads();
  if (threadIdx.x == 0) {
    __hip_atomic_fetch_add(bar, 1u, __ATOMIC_ACQ_REL, __HIP_MEMORY_SCOPE_AGENT);
    while (__hip_atomic_load(bar, __ATOMIC_ACQUIRE, __HIP_MEMORY_SCOPE_AGENT) < target)
      __builtin_amdgcn_s_sleep(8);
    __threadfence();
  }
  __syncthreads();
}

// ---------------------------------------------------------------------------
// Per-WAVE stage of one tile's half (the wave's own 16 rows = 8 KB = 8 DMAs).
// LDS slot s holds global chunk (row = s>>5, c = (s&31) ^ (row&7)) -- source-
// side swizzle because the DMA's LDS dest is wave-uniform base + lane*16
// (m104) and can't scatter.
// ---------------------------------------------------------------------------
__device__ __forceinline__ void stage_half(const float* __restrict__ X, float* XsBuf,
                                           int tile, int wave, int lane) {
#pragma unroll
  for (int j = 0; j < 8; ++j) {
    const int s = 512 * wave + 64 * j + lane;   // slot id within this buffer
    const int row = s >> 5;
    const int c = (s & 31) ^ (row & 7);         // swizzled source chunk
    const float* gp = X + (size_t)tile * (ROWS * DIM) + row * DIM + c * 4;
    __builtin_amdgcn_global_load_lds((g_u32*)gp, (l_u32*)(XsBuf + s * 4), 16, 0, 0);
  }
}

// ---------------------------------------------------------------------------
// Fused kernel. 512 blocks x 128 threads. LDS = 64 KB exactly -> 2 blocks/CU.
// ---------------------------------------------------------------------------
__global__ __launch_bounds__(128, 1) void vqa_fused(const float* __restrict__ X,
                                                    const float* __restrict__ W,
                                                    float* __restrict__ Ur,
                                                    float* __restrict__ Ui,
                                                    unsigned short* __restrict__ Ab,
                                                    unsigned* __restrict__ bars,
                                                    float* __restrict__ out) {
  __shared__ float Xs[DEPTH * ROWS * DIM];   // 4 x 16 KB = 64 KB

  const int tid = threadIdx.x;   // 0..127
  const int lane = tid & 63;
  const int wave = tid >> 6;     // 0..1

  // ---- phase P: prefetch tiles 0..DEPTH-2 (flies under phases A and B) ----
#pragma unroll
  for (int p = 0; p < DEPTH - 1; ++p)
    stage_half(X, Xs + p * (ROWS * DIM), blockIdx.x + p * GRID, wave, lane);

  if (blockIdx.x < DIM) {
    // ---- phase A: register/shuffle sim of circuit column c (wave 0 only) --
    // lane l holds amplitudes of basis indices l (r0) and l+64 (r1).
    // qubit w <-> bit (6-w); mask 64 = in-lane (reg pair), else shfl_xor.
    if (wave == 0) {
      const int c = blockIdx.x;
      float r0r = (lane == c) ? 1.f : 0.f, r0i = 0.f;
      float r1r = (lane + 64 == c) ? 1.f : 0.f, r1i = 0.f;

      for (int l = 0; l < N_LAYERS; ++l) {
        for (int w = 0; w < N_QUBITS; ++w) {
          const float phi = W[(l * 7 + w) * 3 + 0];
          const float th  = W[(l * 7 + w) * 3 + 1];
          const float om  = W[(l * 7 + w) * 3 + 2];
          const float ch = __cosf(0.5f * th), sh = __sinf(0.5f * th);
          const float ap = 0.5f * (phi + om), am = 0.5f * (phi - om);
          const float cap = __cosf(ap), sap = __sinf(ap);
          const float cam = __cosf(am), sam = __sinf(am);
          const float ar =  cap * ch, ai = -sap * ch;
          const float br = -cam * sh, bi = -sam * sh;
          const float cr =  cam * sh, ci = -sam * sh;
          const float dr =  cap * ch, di =  sap * ch;

          const int m = 1 << (6 - w);
          if (m == 64) {
            // pair is (r0, r1) in-lane
            const float n0r = ar * r0r - ai * r0i + br * r1r - bi * r1i;
            const float n0i = ar * r0i + ai * r0r + br * r1i + bi * r1r;
            const float n1r = cr * r0r - ci * r0i + dr * r1r - di * r1i;
            const float n1i = cr * r0i + ci * r0r + dr * r1i + di * r1r;
            r0r = n0r; r0i = n0i; r1r = n1r; r1i = n1i;
          } else {
            const bool hi = (lane & m) != 0;
            const float u_r = hi ? dr : ar, u_i = hi ? di : ai;  // * self
            const float v_r = hi ? cr : br, v_i = hi ? ci : bi;  // * partner
            float pr, pi, nr, ni;
            pr = __shfl_xor(r0r, m, 64); pi = __shfl_xor(r0i, m, 64);
            nr = u_r * r0r - u_i * r0i + v_r * pr - v_i * pi;
            ni = u_r * r0i + u_i * r0r + v_r * pi + v_i * pr;
            r0r = nr; r0i = ni;
            pr = __shfl_xor(r1r, m, 64); pi = __shfl_xor(r1i, m, 64);
            nr = u_r * r1r - u_i * r1i + v_r * pr - v_i * pi;
            ni = u_r * r1i + u_i * r1r + v_r * pi + v_i * pr;
            r1r = nr; r1i = ni;
          }
        }
        const int rr = (l % (N_QUBITS - 1)) + 1;  // ranges [1,2,3,4]
        for (int w = 0; w < N_QUBITS; ++w) {
          const int tgt = (w + rr) % N_QUBITS;
          const int mc = 1 << (6 - w), mt = 1 << (6 - tgt);
          if (mt == 64) {
            // swap r0 <-> r1 where ctrl bit (in-lane index bit) set
            const bool s = (lane & mc) != 0;
            const float t0r = s ? r1r : r0r, t1r = s ? r0r : r1r;
            const float t0i = s ? r1i : r0i, t1i = s ? r0i : r1i;
            r0r = t0r; r1r = t1r; r0i = t0i; r1i = t1i;
          } else if (mc == 64) {
            // ctrl = bit6 = reg1 only: full pair swap within r1
            r1r = __shfl_xor(r1r, mt, 64);
            r1i = __shfl_xor(r1i, mt, 64);
          } else {
            const bool s = (lane & mc) != 0;
            float t;
            t = __shfl_xor(r0r, mt, 64); r0r = s ? t : r0r;
            t = __shfl_xor(r0i, mt, 64); r0i = s ? t : r0i;
            t = __shfl_xor(r1r, mt, 64); r1r = s ? t : r1r;
            t = __shfl_xor(r1i, mt, 64); r1i = s ? t : r1i;
          }
        }
      }
      const int c2 = blockIdx.x;
      Ur[(size_t)lane * DIM + c2]        = r0r;
      Ui[(size_t)lane * DIM + c2]        = r0i;
      Ur[(size_t)(lane + 64) * DIM + c2] = r1r;
      Ui[(size_t)(lane + 64) * DIM + c2] = r1i;
    }
    // barrier 1: among the 128 sim/build blocks only
    grid_bar(&bars[0], DIM);

    // ---- phase B: A row i = blockIdx.x (fp32, identical math to R7) -------
    {
      const int i = blockIdx.x;
      const int j = tid;
      float s = 0.f;
#pragma unroll 8
      for (int k = 0; k < DIM; ++k) {
        const float zk = (((k >> 6) ^ k) & 1) ? -1.f : 1.f;
        s += zk * (Ur[k * DIM + i] * Ur[k * DIM + j] + Ui[k * DIM + i] * Ui[k * DIM + j]);
      }
      Ab[i * DIM + j] = f2bf(s);
    }
  }

  // barrier 2: all 512 blocks; Ab now visible everywhere
  grid_bar(&bars[1], GRID);
  // pin the vmcnt counting base: all prologue DMAs drained by the barrier
  asm volatile("s_waitcnt vmcnt(0)" ::: "memory");

  // ---- phase C: main GEMM loop (R7 body, verified) ------------------------
  const int n16 = lane & 15;
  const int g = lane >> 4;
  const int R = 16 * wave + n16; // this lane's row within the tile (0..31)
  const int rx = R & 7;          // row swizzle key

  // loop-invariant A fragments -> registers (32 x 16 B = 128 VGPRs)
  short8 a_frag[4][8];
#pragma unroll
  for (int kt = 0; kt < 4; ++kt)
#pragma unroll
    for (int t = 0; t < 8; ++t)
      a_frag[kt][t] = *reinterpret_cast<const short8*>(
          Ab + (16 * t + n16) * DIM + 32 * kt + 8 * g);

#pragma unroll 1
  for (int it = 0; it < ITERS; ++it) {
    const int cur = it & (DEPTH - 1);

    // issue tile it+3's DMA into the rotating buffer (wave-private rows)
    if (it + DEPTH - 1 < ITERS)
      stage_half(X, Xs + ((it + DEPTH - 1) & (DEPTH - 1)) * (ROWS * DIM),
                 blockIdx.x + (it + DEPTH - 1) * GRID, wave, lane);

    // counted wait: 8 DMAs/tile/wave, in-order retirement => tile it landed.
    // a_frag loads + out stores only ADD vmcnt ops => stays conservative.
    const int rem = ITERS - 1 - it;
    if (rem >= DEPTH - 1)  asm volatile("s_waitcnt vmcnt(24)" ::: "memory");
    else if (rem == 2)     asm volatile("s_waitcnt vmcnt(16)" ::: "memory");
    else if (rem == 1)     asm volatile("s_waitcnt vmcnt(8)"  ::: "memory");
    else                   asm volatile("s_waitcnt vmcnt(0)"  ::: "memory");

    const int rb = cur * (ROWS * 32) + R * 32;   // row's first slot in cur buf

    // B-fragments from LDS
    short8 bfrag[4];
#pragma unroll
    for (int kt = 0; kt < 4; ++kt) {
      const int c0 = 8 * kt + 2 * g;
      const float4 lo = *reinterpret_cast<const float4*>(Xs + (rb + (c0 ^ rx)) * 4);
      const float4 hi = *reinterpret_cast<const float4*>(Xs + (rb + ((c0 + 1) ^ rx)) * 4);
      bfrag[kt] = pack_bf16(lo, hi);
    }

    f32x4 acc[8];
#pragma unroll
    for (int t = 0; t < 8; ++t) acc[t] = (f32x4){0.f, 0.f, 0.f, 0.f};
#pragma unroll
    for (int kt = 0; kt < 4; ++kt) {
#pragma unroll
      for (int t = 0; t < 8; ++t)
        acc[t] = __builtin_amdgcn_mfma_f32_16x16x32_bf16(a_frag[kt][t], bfrag[kt],
                                                         acc[t], 0, 0, 0);
    }

    // epilogue: x re-read from cur buffer (not overwritten until it+1's stage)
    float dot = 0.f, nrm = 0.f;
#pragma unroll
    for (int t = 0; t < 8; ++t) {
      const float4 xe = *reinterpret_cast<const float4*>(Xs + (rb + ((4 * t + g) ^ rx)) * 4);
      dot += xe.x * acc[t][0] + xe.y * acc[t][1] + xe.z * acc[t][2] + xe.w * acc[t][3];
      nrm += xe.x * xe.x + xe.y * xe.y + xe.z * xe.z + xe.w * xe.w;
    }
    dot += __shfl_xor(dot, 16, 64);
    dot += __shfl_xor(dot, 32, 64);
    nrm += __shfl_xor(nrm, 16, 64);
    nrm += __shfl_xor(nrm, 32, 64);
    if (g == 0) out[(blockIdx.x + it * GRID) * ROWS + R] = dot / nrm;
  }
}

// ---------------------------------------------------------------------------
extern "C" void kernel_launch(void* const* d_in, const int* in_sizes, int n_in,
                              void* d_out, int out_size, void* d_ws, size_t ws_size,
                              hipStream_t stream) {
  const float* X = (const float*)d_in[0];   // (262144, 128) fp32
  const float* W = (const float*)d_in[1];   // (4, 7, 3) fp32
  float* out = (float*)d_out;               // (262144,) fp32

  float* Ur = (float*)d_ws;
  float* Ui = Ur + DIM * DIM;
  unsigned short* Ab = (unsigned short*)(Ui + DIM * DIM);
  unsigned* bars = (unsigned*)(Ab + DIM * DIM);

  // zero the barrier counters (ws is re-poisoned before each iteration);
  // same-stream + graph-capture-safe (harness itself enqueues memsets)
  hipMemsetAsync(bars, 0, 2 * sizeof(unsigned), stream);

  vqa_fused<<<GRID, 128, 0, stream>>>(X, W, Ur, Ui, Ab, bars, out);
}

// Round 4
// 216.112 us; speedup vs baseline: 1.5319x; 1.5319x over previous
//
#include <hip/hip_runtime.h>

// ---------------------------------------------------------------------------
// out[n] = x_n^T A x_n / (x_n^T x_n),  A = Re(U^H Z U), U = full circuit unitary
// Kernel 1: simulate circuit on 128 basis columns -> U (complex fp32) in ws
// Kernel 2: A_ij = sum_k z_k (Ur_ki Ur_kj + Ui_ki Ui_kj) -> bf16 A in ws
// Kernel 3: bf16 MFMA GEMM y = A x fused with dot/norm epilogue
//
// R9 -> R10: R9's counters: fused kernel 200 us at 1.6% MfmaUtil / 4.3% HBM /
// 11.5% occupancy -> ~97% waiting; the manual grid barrier (512 leader
// atomics on one cacheline across 8 XCD L2s) cost ~130 us. Also R6==R7
// timing proved phase C was never drain-bound: its ~60 us is the LDS-DMA
// round trip exposed at 1 wave/SIMD. R10: back to 3 kernels, and kernel 3
// drops LDS ENTIRELY:
//   - B-fragments loaded directly from global as float4 (lo/hi pairs fully
//     cover each 128B line; epilogue xe re-reads hit L1). Same float values,
//     same op order as R7 -> bit-identical numerics.
//   - A held in 128 VGPRs (unchanged). No LDS -> no global_load_lds, no
//     ds_read, no vmcnt asm, no bank conflicts, no barriers.
//   - occupancy 4 -> 8 waves/CU (VGPR-capped, __launch_bounds__(128,2));
//     GRID 512 -> 1024 (ITERS 8) to fill the 4-blocks/CU capacity.
//   - 1-tile-ahead prefetch: next tile's 4 'lo' loads touch all 64 lines of
//     the next 16 rows -> HBM latency absorbed at prefetch, consumption is
//     L1-hits; 2 waves/SIMD cover the residue.
// Predicted: vqa_main 60-70 -> 25-40 us (>=3.5 TB/s on its dispatch,
// LDS_BANK_CONFLICT ~0, VGPR ~250); bench 331 -> ~170-190 (131 us is
// harness-fixed). absmax unchanged: 0.001953125.
// ---------------------------------------------------------------------------

#define N_QUBITS 7
#define DIM 128
#define N_LAYERS 4
#define BATCH 262144
#define GRID 1024
#define ROWS 32                          // rows per tile (16 per wave)
#define ITERS (BATCH / (GRID * ROWS))    // 8

typedef short short8 __attribute__((ext_vector_type(8)));
typedef float f32x4 __attribute__((ext_vector_type(4)));

__device__ __forceinline__ unsigned short f2bf(float f) {
  unsigned u = __builtin_bit_cast(unsigned, f);
  u += 0x7fffu + ((u >> 16) & 1u);   // RNE
  return (unsigned short)(u >> 16);
}

// [bf16(x) | bf16(y)<<16]: round-half-up add + v_perm byte select
__device__ __forceinline__ unsigned pk2(float x, float y) {
  unsigned ux = __builtin_bit_cast(unsigned, x) + 0x8000u;
  unsigned uy = __builtin_bit_cast(unsigned, y) + 0x8000u;
  return __builtin_amdgcn_perm(uy, ux, 0x07060302u);
}

__device__ __forceinline__ short8 pack_bf16(float4 lo, float4 hi) {
  uint4 d;
  d.x = pk2(lo.x, lo.y);
  d.y = pk2(lo.z, lo.w);
  d.z = pk2(hi.x, hi.y);
  d.w = pk2(hi.z, hi.w);
  return __builtin_bit_cast(short8, d);
}

// ---------------------------------------------------------------------------
// Kernel 1: one block (64 threads) per column c. State (128 complex) in LDS.
// Qubit w <-> bit (6-w) of the flattened index.  (unchanged, verified)
// ---------------------------------------------------------------------------
__global__ void sim_columns(const float* __restrict__ W,
                            float* __restrict__ Ur, float* __restrict__ Ui) {
  __shared__ float sr[DIM], si[DIM];
  const int c = blockIdx.x;
  const int t = threadIdx.x;  // 0..63

  sr[t] = (t == c) ? 1.f : 0.f;        si[t] = 0.f;
  sr[t + 64] = (t + 64 == c) ? 1.f : 0.f;  si[t + 64] = 0.f;
  __syncthreads();

  for (int l = 0; l < N_LAYERS; ++l) {
    for (int w = 0; w < N_QUBITS; ++w) {
      const float phi = W[(l * 7 + w) * 3 + 0];
      const float th  = W[(l * 7 + w) * 3 + 1];
      const float om  = W[(l * 7 + w) * 3 + 2];
      const float ch = __cosf(0.5f * th), sh = __sinf(0.5f * th);
      const float ap = 0.5f * (phi + om), am = 0.5f * (phi - om);
      const float cap = __cosf(ap), sap = __sinf(ap);
      const float cam = __cosf(am), sam = __sinf(am);
      const float ar =  cap * ch, ai = -sap * ch;
      const float br = -cam * sh, bi = -sam * sh;
      const float cr =  cam * sh, ci = -sam * sh;
      const float dr =  cap * ch, di =  sap * ch;

      const int m = 1 << (6 - w);
      const int i0 = ((t & ~(m - 1)) << 1) | (t & (m - 1));
      const int i1 = i0 | m;
      const float x0r = sr[i0], x0i = si[i0];
      const float x1r = sr[i1], x1i = si[i1];
      __syncthreads();
      sr[i0] = ar * x0r - ai * x0i + br * x1r - bi * x1i;
      si[i0] = ar * x0i + ai * x0r + br * x1i + bi * x1r;
      sr[i1] = cr * x0r - ci * x0i + dr * x1r - di * x1i;
      si[i1] = cr * x0i + ci * x0r + dr * x1i + di * x1r;
      __syncthreads();
    }
    const int r = (l % (N_QUBITS - 1)) + 1;  // ranges [1,2,3,4]
    for (int w = 0; w < N_QUBITS; ++w) {
      const int ctrl = w, tgt = (w + r) % N_QUBITS;
      const int cmask = 1 << (6 - ctrl), tmask = 1 << (6 - tgt);
      const int i0 = ((t & ~(tmask - 1)) << 1) | (t & (tmask - 1));
      const int i1 = i0 | tmask;
      const float a0r = sr[i0], a0i = si[i0];
      const float a1r = sr[i1], a1i = si[i1];
      __syncthreads();
      if (i0 & cmask) {
        sr[i0] = a1r; si[i0] = a1i;
        sr[i1] = a0r; si[i1] = a0i;
      }
      __syncthreads();
    }
  }
  Ur[(size_t)t * DIM + c]        = sr[t];
  Ui[(size_t)t * DIM + c]        = si[t];
  Ur[(size_t)(t + 64) * DIM + c] = sr[t + 64];
  Ui[(size_t)(t + 64) * DIM + c] = si[t + 64];
}

// ---------------------------------------------------------------------------
// Kernel 2: A_ij, identity k-layout. 128 blocks (row i) x 128 threads (j).
// Ur[k][i] broadcasts; Ur[k][j] coalesces; all L2-hot.  (unchanged, verified)
// ---------------------------------------------------------------------------
__global__ void build_A(const float* __restrict__ Ur, const float* __restrict__ Ui,
                        unsigned short* __restrict__ Ab) {
  const int i = blockIdx.x;
  const int j = threadIdx.x;
  float s = 0.f;
#pragma unroll 8
  for (int k = 0; k < DIM; ++k) {
    const float zk = (((k >> 6) ^ k) & 1) ? -1.f : 1.f;
    s += zk * (Ur[k * DIM + i] * Ur[k * DIM + j] + Ui[k * DIM + i] * Ui[k * DIM + j]);
  }
  Ab[i * DIM + j] = f2bf(s);
}

// ---------------------------------------------------------------------------
// Kernel 3. LDS-free. Block = 2 waves; wave w owns tile rows 16w..16w+15.
//   A-frag: a_frag[kt][t] = Ab[16t + n16][32kt + 8g .. +8]   (128 VGPRs)
//   B-frag: lane (n16,g) needs x[R][32kt + 8g .. +8] = lo(chunk 8kt+2g) +
//           hi(chunk 8kt+2g+1), loaded as two float4 from global. Per row,
//           the 4 g-lanes' lo-chunks {0,32,64,96}+128kt fill one 128B line;
//           hi fills its other half -> lines fully covered, L1-resident.
//   C/D:    acc[t][r] = y[16t + 4g + r][row R]; epilogue xe = chunk (4t+g),
//           re-read from L1. Identical float values / op order to R7.
// Prefetch: next tile's 4 lo-loads touch all 64 lines of its 16 rows.
// ---------------------------------------------------------------------------
__global__ __launch_bounds__(128, 2) void vqa_main(const float* __restrict__ X,
                                                   const unsigned short* __restrict__ Ab,
                                                   float* __restrict__ out) {
  const int tid = threadIdx.x;   // 0..127
  const int lane = tid & 63;
  const int wave = tid >> 6;     // 0..1
  const int n16 = lane & 15;
  const int g = lane >> 4;
  const int R = 16 * wave + n16; // this lane's row within the tile (0..31)

  // this lane's row pointer within tile 0, and per-iteration stride
  const size_t step = (size_t)GRID * ROWS * DIM;
  const float* p = X + (size_t)blockIdx.x * (ROWS * DIM) + R * DIM;

  // prologue: current tile's lo chunks (also pulls all 64 lines of the tile)
  float4 lo[4];
#pragma unroll
  for (int kt = 0; kt < 4; ++kt)
    lo[kt] = *reinterpret_cast<const float4*>(p + 32 * kt + 8 * g);

  // loop-invariant A fragments -> registers (32 x 16 B = 128 VGPRs); L2-hot
  short8 a_frag[4][8];
#pragma unroll
  for (int kt = 0; kt < 4; ++kt)
#pragma unroll
    for (int t = 0; t < 8; ++t)
      a_frag[kt][t] = *reinterpret_cast<const short8*>(
          Ab + (16 * t + n16) * DIM + 32 * kt + 8 * g);

#pragma unroll 1
  for (int it = 0; it < ITERS; ++it) {
    // hi chunks: same lines as lo -> L1 hits
    float4 hi[4];
#pragma unroll
    for (int kt = 0; kt < 4; ++kt)
      hi[kt] = *reinterpret_cast<const float4*>(p + 32 * kt + 8 * g + 4);

    // prefetch next tile's lo (brings every line of the next 16 rows)
    float4 nlo[4];
    const bool more = (it + 1 < ITERS);
    if (more) {
#pragma unroll
      for (int kt = 0; kt < 4; ++kt)
        nlo[kt] = *reinterpret_cast<const float4*>(p + step + 32 * kt + 8 * g);
    }

    short8 bfrag[4];
#pragma unroll
    for (int kt = 0; kt < 4; ++kt)
      bfrag[kt] = pack_bf16(lo[kt], hi[kt]);

    f32x4 acc[8];
#pragma unroll
    for (int t = 0; t < 8; ++t) acc[t] = (f32x4){0.f, 0.f, 0.f, 0.f};
#pragma unroll
    for (int kt = 0; kt < 4; ++kt) {
#pragma unroll
      for (int t = 0; t < 8; ++t)
        acc[t] = __builtin_amdgcn_mfma_f32_16x16x32_bf16(a_frag[kt][t], bfrag[kt],
                                                         acc[t], 0, 0, 0);
    }

    // epilogue: xe chunks (4t+g) re-read from L1 (same lines as lo/hi)
    float dot = 0.f, nrm = 0.f;
#pragma unroll
    for (int t = 0; t < 8; ++t) {
      const float4 xe = *reinterpret_cast<const float4*>(p + 16 * t + 4 * g);
      dot += xe.x * acc[t][0] + xe.y * acc[t][1] + xe.z * acc[t][2] + xe.w * acc[t][3];
      nrm += xe.x * xe.x + xe.y * xe.y + xe.z * xe.z + xe.w * xe.w;
    }
    dot += __shfl_xor(dot, 16, 64);
    dot += __shfl_xor(dot, 32, 64);
    nrm += __shfl_xor(nrm, 16, 64);
    nrm += __shfl_xor(nrm, 32, 64);
    if (g == 0) out[(blockIdx.x + it * GRID) * ROWS + R] = dot / nrm;

    if (more) {
#pragma unroll
      for (int kt = 0; kt < 4; ++kt) lo[kt] = nlo[kt];
    }
    p += step;
  }
}

// ---------------------------------------------------------------------------
extern "C" void kernel_launch(void* const* d_in, const int* in_sizes, int n_in,
                              void* d_out, int out_size, void* d_ws, size_t ws_size,
                              hipStream_t stream) {
  const float* X = (const float*)d_in[0];   // (262144, 128) fp32
  const float* W = (const float*)d_in[1];   // (4, 7, 3) fp32
  float* out = (float*)d_out;               // (262144,) fp32

  float* Ur = (float*)d_ws;
  float* Ui = Ur + DIM * DIM;
  unsigned short* Ab = (unsigned short*)(Ui + DIM * DIM);

  sim_columns<<<DIM, 64, 0, stream>>>(W, Ur, Ui);
  build_A<<<DIM, DIM, 0, stream>>>(Ur, Ui, Ab);
  vqa_main<<<GRID, 128, 0, stream>>>(X, Ab, out);
}